// Round 3
// baseline (709.782 us; speedup 1.0000x reference)
//
#include <hip/hip_runtime.h>
#include <hip/hip_bf16.h>
#include <math.h>

#define L_TAU_C 0.8f

typedef __attribute__((ext_vector_type(8))) _Float16 half8_t;

__device__ __forceinline__ float sigmoidf_(float x) {
    return 1.0f / (1.0f + __expf(-x));
}

// ---------------------------------------------------------------------------
// Kernel 1: transpose x [128][4096][20] f32 -> xT [128][20][4096] f16.
// ---------------------------------------------------------------------------
__global__ __launch_bounds__(256) void k_transpose16(const float* __restrict__ x,
                                                     _Float16* __restrict__ xT) {
    int gp = blockIdx.x * 256 + threadIdx.x;      // 0..524287
    int b = gp >> 12, p = gp & 4095;
    const float4* src = reinterpret_cast<const float4*>(x + (size_t)gp * 20);
    float v[20];
#pragma unroll
    for (int k = 0; k < 5; ++k) {
        float4 q = src[k];
        v[4 * k + 0] = q.x; v[4 * k + 1] = q.y; v[4 * k + 2] = q.z; v[4 * k + 3] = q.w;
    }
    _Float16* dst = xT + (size_t)b * 20 * 4096 + p;
#pragma unroll
    for (int t = 0; t < 20; ++t) dst[(size_t)t * 4096] = (_Float16)v[t];
}

// ---------------------------------------------------------------------------
// Kernel 2: fused conv + SNU(s1,y1) + maxpool + partial FC dot.
// Grid = 768 (b,ch), XCD-swizzled. Block = 256 threads (4 waves), 243 active:
// thread = (pool row r 0..26, col group cg 0..8) -> 2 conv rows x 6 conv cols.
// xs LDS [64 rows][16 float4-units], XOR-swizzled u' = u ^ ((R>>1)&15).
// Conv weights staged in LDS, read as float2 broadcasts (conflict-free,
// lgkmcnt-pipelined -- NOT s_load, which drains ds_read queues).
// Seg extraction: 5 aligned b128 reads + 15 cndmask (off in {0,2}).
// ---------------------------------------------------------------------------
template<int XMODE>   // 1 = f16 transposed input, 0 = strided fallback
__global__ __launch_bounds__(256) void k_conv_snu(
    const float* __restrict__ x,      // [128][4096][20]
    const _Float16* __restrict__ xT,  // [128][20][4096]
    const float* __restrict__ Wc,     // [6][1][10][10]
    const float* __restrict__ bc,     // [6]
    const float* __restrict__ W2,     // [4374][2]
    float* __restrict__ part)         // [20][128][6][2]
{
    __shared__ float xs[64 * 64];     // 16 KB, swizzled in 16B units
    __shared__ float wsh[100];
    __shared__ float red[8];
    float4* xs4 = reinterpret_cast<float4*>(xs);
    const float2* wsh2 = reinterpret_cast<const float2*>(wsh);

    const int tid = threadIdx.x;
    const int bi = blockIdx.x;
    const int xcd = bi & 7, slot = bi >> 3;
    const int b = (slot / 6) * 8 + xcd;   // all 6 ch of b on same XCD
    const int ch = slot % 6;

    if (tid < 100) wsh[tid] = Wc[ch * 100 + tid];

    const bool active = tid < 243;
    const int r = tid / 9;            // pool row 0..26
    const int cg = tid % 9;           // col group 0..8, 6 conv cols each
    const int row0 = 2 * r;
    const int u0 = (3 * cg) >> 1;     // first 16B unit covering col 6*cg
    const bool offs = (cg & 1);       // off = 2 when cg odd, else 0

    float s1[2][6], y1[2][6];
#pragma unroll
    for (int i = 0; i < 2; ++i)
#pragma unroll
        for (int j = 0; j < 6; ++j) { s1[i][j] = 0.f; y1[i][j] = 0.f; }

    const float bch = bc[ch];

    float w2r[3][2];
#pragma unroll
    for (int pj = 0; pj < 3; ++pj) { w2r[pj][0] = 0.f; w2r[pj][1] = 0.f; }
    if (active) {
        int f0 = ch * 729 + r * 27 + cg * 3;
#pragma unroll
        for (int pj = 0; pj < 3; ++pj) {
            w2r[pj][0] = W2[(size_t)(f0 + pj) * 2 + 0];
            w2r[pj][1] = W2[(size_t)(f0 + pj) * 2 + 1];
        }
    }

    const int wave = tid >> 6, lane = tid & 63;

    for (int t = 0; t < 20; ++t) {
        __syncthreads();   // xs/red of t-1 consumed; wsh visible (t=0)
        // ---- stage x_t into swizzled xs ----
        if (XMODE == 1) {
            const _Float16* src = xT + ((size_t)b * 20 + t) * 4096;
#pragma unroll
            for (int k = 0; k < 2; ++k) {
                int e = tid + k * 256;          // 512 half8 units
                half8_t hv = *reinterpret_cast<const half8_t*>(src + e * 8);
                int R = e >> 3, h = e & 7;
                int sw = (R >> 1) & 15;
                float4 fa, fb;
                fa.x = (float)hv[0]; fa.y = (float)hv[1];
                fa.z = (float)hv[2]; fa.w = (float)hv[3];
                fb.x = (float)hv[4]; fb.y = (float)hv[5];
                fb.z = (float)hv[6]; fb.w = (float)hv[7];
                xs4[(R << 4) + ((2 * h) ^ sw)] = fa;
                xs4[(R << 4) + ((2 * h + 1) ^ sw)] = fb;
            }
        } else {
#pragma unroll
            for (int k = 0; k < 16; ++k) {
                int p = tid + k * 256;
                int R = p >> 6, c = p & 63;
                int sw = (R >> 1) & 15;
                float vv = x[((size_t)b * 4096 + p) * 20 + t];
                xs[(R << 6) + ((((c >> 2) ^ sw) & 15) << 2) + (c & 3)] = vv;
            }
        }
        __syncthreads();

        float p0 = 0.f, p1 = 0.f;
        if (active) {
            float c0[6], c1[6];
#pragma unroll
            for (int j = 0; j < 6; ++j) { c0[j] = 0.f; c1[j] = 0.f; }

#pragma unroll
            for (int xr = 0; xr < 11; ++xr) {
                const int R = row0 + xr;
                const int sw = (R >> 1) & 15;
                float4 sg[5];
#pragma unroll
                for (int q = 0; q < 5; ++q)
                    sg[q] = xs4[(R << 4) + (((u0 + q) ^ sw) & 15)];
                const float* f = reinterpret_cast<const float*>(sg);
                float seg[15];
#pragma unroll
                for (int j = 0; j < 15; ++j) seg[j] = offs ? f[j + 2] : f[j];

                if (xr <= 9) {
#pragma unroll
                    for (int kc2 = 0; kc2 < 5; ++kc2) {
                        float2 w = wsh2[xr * 5 + kc2];
#pragma unroll
                        for (int j = 0; j < 6; ++j) {
                            c0[j] += seg[j + 2 * kc2] * w.x;
                            c0[j] += seg[j + 2 * kc2 + 1] * w.y;
                        }
                    }
                }
                if (xr >= 1) {
#pragma unroll
                    for (int kc2 = 0; kc2 < 5; ++kc2) {
                        float2 w = wsh2[(xr - 1) * 5 + kc2];
#pragma unroll
                        for (int j = 0; j < 6; ++j) {
                            c1[j] += seg[j + 2 * kc2] * w.x;
                            c1[j] += seg[j + 2 * kc2 + 1] * w.y;
                        }
                    }
                }
            }
            // SNU: s = relu(c + 0.8*s*(1-y)); y = sigmoid(s + bc)
#pragma unroll
            for (int j = 0; j < 6; ++j) {
                float sa = fmaxf(c0[j] + L_TAU_C * s1[0][j] * (1.f - y1[0][j]), 0.f);
                float sb = fmaxf(c1[j] + L_TAU_C * s1[1][j] * (1.f - y1[1][j]), 0.f);
                s1[0][j] = sa; s1[1][j] = sb;
                y1[0][j] = sigmoidf_(sa + bch);
                y1[1][j] = sigmoidf_(sb + bch);
            }
            // maxpool 2x2 + partial FC dot
#pragma unroll
            for (int pj = 0; pj < 3; ++pj) {
                float h = fmaxf(fmaxf(y1[0][2 * pj], y1[0][2 * pj + 1]),
                                fmaxf(y1[1][2 * pj], y1[1][2 * pj + 1]));
                p0 += h * w2r[pj][0];
                p1 += h * w2r[pj][1];
            }
        }
        // block reduce p0,p1 (inactive lanes contribute 0)
#pragma unroll
        for (int off = 32; off >= 1; off >>= 1) {
            p0 += __shfl_down(p0, off);
            p1 += __shfl_down(p1, off);
        }
        if (lane == 0) { red[wave * 2] = p0; red[wave * 2 + 1] = p1; }
        __syncthreads();
        if (tid == 0) {
            float q0 = red[0] + red[2] + red[4] + red[6];
            float q1 = red[1] + red[3] + red[5] + red[7];
            float* dst = part + ((size_t)t * 128 + b) * 12 + ch * 2;
            dst[0] = q0; dst[1] = q1;
        }
    }
}

// ---------------------------------------------------------------------------
// Kernel 3: s2/y2 recurrence, out_rec, m, loss, acc. One block, 128 threads.
// ---------------------------------------------------------------------------
__global__ __launch_bounds__(128) void k_final(const float* __restrict__ part,
                                               const void* __restrict__ yraw,
                                               const float* __restrict__ b2,
                                               float* __restrict__ out) {
    __shared__ float red[4];
    const int b = threadIdx.x;  // 0..127

    // labels may be int64 (reference) or int32: detect.
    const int* yi = (const int*)yraw;
    bool i64 = true;
    for (int k = 0; k < 64; ++k) {
        if (yi[2 * k + 1] != 0) { i64 = false; break; }
    }
    int lbl = i64 ? (int)((const long long*)yraw)[b] : yi[b];

    float b20 = b2[0], b21 = b2[1];
    float s20 = 0.f, s21 = 0.f, y20 = 0.f, y21 = 0.f, m0 = 0.f, m1 = 0.f;
    float* orec = out + 257 + b * 42;
    orec[0] = 0.f; orec[1] = 0.f;
    for (int t = 0; t < 20; ++t) {
        const float4* pp = reinterpret_cast<const float4*>(part + ((size_t)t * 128 + b) * 12);
        float4 a = pp[0], c = pp[1], d = pp[2];
        float sum0 = a.x + a.z + c.x + c.z + d.x + d.z;
        float sum1 = a.y + a.w + c.y + c.w + d.y + d.w;
        s20 = fmaxf(sum0 + L_TAU_C * s20 * (1.f - y20), 0.f);
        s21 = fmaxf(sum1 + L_TAU_C * s21 * (1.f - y21), 0.f);
        y20 = sigmoidf_(s20 + b20);
        y21 = sigmoidf_(s21 + b21);
        orec[(t + 1) * 2 + 0] = y20;
        orec[(t + 1) * 2 + 1] = y21;
        m0 += y20; m1 += y21;
    }
    m0 *= 0.05f; m1 *= 0.05f;
    out[1 + b * 2 + 0] = m0;
    out[1 + b * 2 + 1] = m1;

    float mx = fmaxf(m0, m1);
    float lse = mx + logf(expf(m0 - mx) + expf(m1 - mx));
    float lossc = -(((lbl != 0) ? m1 : m0) - lse);
    int pred = (m1 > m0) ? 1 : 0;
    float accc = (pred == lbl) ? 1.f : 0.f;
#pragma unroll
    for (int off = 32; off >= 1; off >>= 1) {
        lossc += __shfl_down(lossc, off);
        accc += __shfl_down(accc, off);
    }
    if ((b & 63) == 0) { red[(b >> 6) * 2] = lossc; red[(b >> 6) * 2 + 1] = accc; }
    __syncthreads();
    if (b == 0) {
        out[0] = (red[0] + red[2]) * (1.f / 128.f);
        out[5633] = (red[1] + red[3]) * (1.f / 128.f);
    }
}

extern "C" void kernel_launch(void* const* d_in, const int* in_sizes, int n_in,
                              void* d_out, int out_size, void* d_ws, size_t ws_size,
                              hipStream_t stream) {
    const float* x  = (const float*)d_in[0];
    const void*  y  = d_in[1];
    const float* Wc = (const float*)d_in[2];
    const float* bc = (const float*)d_in[3];
    const float* W2 = (const float*)d_in[4];
    const float* b2 = (const float*)d_in[5];
    float* out = (float*)d_out;

    const size_t xt_bytes = (size_t)128 * 20 * 4096 * 2;    // 20,971,520
    const size_t part_bytes = (size_t)20 * 128 * 6 * 2 * 4; // 245,760
    const int use16 = (ws_size >= xt_bytes + part_bytes) ? 1 : 0;

    _Float16* xT = (_Float16*)d_ws;
    float* part = use16 ? (float*)((char*)d_ws + xt_bytes) : (float*)d_ws;

    if (use16) {
        k_transpose16<<<2048, 256, 0, stream>>>(x, xT);
        k_conv_snu<1><<<768, 256, 0, stream>>>(x, xT, Wc, bc, W2, part);
    } else {
        k_conv_snu<0><<<768, 256, 0, stream>>>(x, (const _Float16*)d_ws, Wc, bc, W2, part);
    }
    k_final<<<1, 128, 0, stream>>>(part, y, b2, out);
}

// Round 4
// 182.932 us; speedup vs baseline: 3.8800x; 3.8800x over previous
//
#include <hip/hip_runtime.h>
#include <hip/hip_bf16.h>
#include <math.h>

#define L_TAU_C 0.8f

typedef __attribute__((ext_vector_type(8))) _Float16 half8_t;

__device__ __forceinline__ float sigmoidf_(float x) {
    return 1.0f / (1.0f + __expf(-x));
}

// ---------------------------------------------------------------------------
// Kernel 1: transpose x [128][4096][20] f32 -> xT [128][20][4096] f16.
// ---------------------------------------------------------------------------
__global__ __launch_bounds__(256) void k_transpose16(const float* __restrict__ x,
                                                     _Float16* __restrict__ xT) {
    int gp = blockIdx.x * 256 + threadIdx.x;      // 0..524287
    int b = gp >> 12, p = gp & 4095;
    const float4* src = reinterpret_cast<const float4*>(x + (size_t)gp * 20);
    float v[20];
#pragma unroll
    for (int k = 0; k < 5; ++k) {
        float4 q = src[k];
        v[4 * k + 0] = q.x; v[4 * k + 1] = q.y; v[4 * k + 2] = q.z; v[4 * k + 3] = q.w;
    }
    _Float16* dst = xT + (size_t)b * 20 * 4096 + p;
#pragma unroll
    for (int t = 0; t < 20; ++t) dst[(size_t)t * 4096] = (_Float16)v[t];
}

// ---------------------------------------------------------------------------
// Kernel 2: fused conv + SNU(s1,y1) + maxpool + partial FC dot.
// Grid = 768 (b,ch) XCD-swizzled; block = 256 (4 waves), 243 active:
// thread = (pool row r 0..26, col group cg 0..8) -> 2 conv rows x 6 cols.
// DUAL LDS copies of the x_t row tile: copy A = as-is, copy B = shifted
// left by 2 floats. Even cg reads A (6cg%4==0), odd cg reads B
// ((6cg-2)%4==0) -> every window is 4 aligned ds_read_b128, ALL indices
// compile-time (no runtime-indexed local arrays -> no scratch).
// Both copies XOR-swizzled in 16B units: u' = u ^ ((R>>1)&15).
// Conv weights in LDS, float2 broadcasts; previous row carried in regs.
// ---------------------------------------------------------------------------
template<int XMODE>   // 1 = f16 transposed input, 0 = strided fallback
__global__ __launch_bounds__(256) void k_conv_snu(
    const float* __restrict__ x,      // [128][4096][20]
    const _Float16* __restrict__ xT,  // [128][20][4096]
    const float* __restrict__ Wc,     // [6][1][10][10]
    const float* __restrict__ bc,     // [6]
    const float* __restrict__ W2,     // [4374][2]
    float* __restrict__ part)         // [20][128][6][2]
{
    __shared__ float xs[2 * 64 * 64];   // 32 KB: A at [0], B(shift2) at [4096]
    __shared__ float wsh[100];
    __shared__ float red[8];
    float4* xs4 = reinterpret_cast<float4*>(xs);
    const float2* wsh2 = reinterpret_cast<const float2*>(wsh);

    const int tid = threadIdx.x;
    const int bi = blockIdx.x;
    const int xcd = bi & 7, slot = bi >> 3;
    const int b = (slot / 6) * 8 + xcd;   // all 6 ch of b on same XCD
    const int ch = slot % 6;

    if (tid < 100) wsh[tid] = Wc[ch * 100 + tid];

    const bool active = tid < 243;
    const int r = tid / 9;            // pool row 0..26
    const int cg = tid % 9;           // col group 0..8, 6 conv cols each
    const int row0 = 2 * r;
    const int codd = cg & 1;
    const int u0 = (6 * cg - 2 * codd) >> 2;   // aligned start unit, 0..12
    const int cb4 = codd << 10;                // float4-index base of copy

    float s1[2][6], y1[2][6];
#pragma unroll
    for (int i = 0; i < 2; ++i)
#pragma unroll
        for (int j = 0; j < 6; ++j) { s1[i][j] = 0.f; y1[i][j] = 0.f; }

    const float bch = bc[ch];

    float w2r[3][2];
#pragma unroll
    for (int pj = 0; pj < 3; ++pj) { w2r[pj][0] = 0.f; w2r[pj][1] = 0.f; }
    if (active) {
        int f0 = ch * 729 + r * 27 + cg * 3;
#pragma unroll
        for (int pj = 0; pj < 3; ++pj) {
            w2r[pj][0] = W2[(size_t)(f0 + pj) * 2 + 0];
            w2r[pj][1] = W2[(size_t)(f0 + pj) * 2 + 1];
        }
    }

    const int wave = tid >> 6, lane = tid & 63;

    for (int t = 0; t < 20; ++t) {
        __syncthreads();   // xs/red of t-1 consumed; wsh visible (t=0)
        // ---- stage x_t into BOTH swizzled copies ----
        if (XMODE == 1) {
            const _Float16* src = xT + ((size_t)b * 20 + t) * 4096;
#pragma unroll
            for (int k = 0; k < 2; ++k) {
                int e = tid + k * 256;          // 512 half8 units (8 floats)
                half8_t hv = *reinterpret_cast<const half8_t*>(src + e * 8);
                int R = e >> 3, h = e & 7;      // cols [8h, 8h+8) of row R
                int sw = (R >> 1) & 15;
                float f0v = (float)hv[0], f1v = (float)hv[1];
                float f2v = (float)hv[2], f3v = (float)hv[3];
                float f4v = (float)hv[4], f5v = (float)hv[5];
                float f6v = (float)hv[6], f7v = (float)hv[7];
                // copy A
                float4 fa = {f0v, f1v, f2v, f3v};
                float4 fb = {f4v, f5v, f6v, f7v};
                xs4[(R << 4) + ((2 * h) ^ sw)] = fa;
                xs4[(R << 4) + ((2 * h + 1) ^ sw)] = fb;
                // copy B: col c -> position c-2
                float4 mid = {f2v, f3v, f4v, f5v};          // pos 8h..8h+3
                xs4[1024 + (R << 4) + ((2 * h) ^ sw)] = mid;
                float2 hi = {f6v, f7v};                     // pos 8h+4,8h+5
                *reinterpret_cast<float2*>(
                    &xs[4096 + (R << 6) + (((2 * h + 1) ^ sw) << 2)]) = hi;
                if (h > 0) {
                    float2 lo = {f0v, f1v};                 // pos 8h-2,8h-1
                    *reinterpret_cast<float2*>(
                        &xs[4096 + (R << 6) + (((2 * h - 1) ^ sw) << 2) + 2]) = lo;
                }
            }
        } else {
#pragma unroll
            for (int k = 0; k < 16; ++k) {
                int p = tid + k * 256;
                int R = p >> 6, c = p & 63;
                int sw = (R >> 1) & 15;
                float vv = x[((size_t)b * 4096 + p) * 20 + t];
                xs[(R << 6) + ((((c >> 2) ^ sw) & 15) << 2) + (c & 3)] = vv;
                if (c >= 2) {
                    int q = c - 2;
                    xs[4096 + (R << 6) + (((q >> 2) ^ sw) << 2) + (q & 3)] = vv;
                }
            }
        }
        __syncthreads();

        float p0 = 0.f, p1 = 0.f;
        if (active) {
            float c0[6], c1[6];
#pragma unroll
            for (int j = 0; j < 6; ++j) { c0[j] = 0.f; c1[j] = 0.f; }
            float wprev[10];

#pragma unroll
            for (int xr = 0; xr < 11; ++xr) {
                const int R = row0 + xr;
                const int sw = (R >> 1) & 15;
                const int rb = cb4 + (R << 4);
                float4 q0 = xs4[rb + ((u0 + 0) ^ sw)];
                float4 q1 = xs4[rb + ((u0 + 1) ^ sw)];
                float4 q2 = xs4[rb + ((u0 + 2) ^ sw)];
                float4 q3 = xs4[rb + ((u0 + 3) ^ sw)];
                float seg[16] = {q0.x, q0.y, q0.z, q0.w,
                                 q1.x, q1.y, q1.z, q1.w,
                                 q2.x, q2.y, q2.z, q2.w,
                                 q3.x, q3.y, q3.z, q3.w};
                float wcur[10];
                if (xr <= 9) {
#pragma unroll
                    for (int kc2 = 0; kc2 < 5; ++kc2) {
                        float2 w = wsh2[xr * 5 + kc2];
                        wcur[2 * kc2] = w.x; wcur[2 * kc2 + 1] = w.y;
                    }
#pragma unroll
                    for (int kc = 0; kc < 10; ++kc)
#pragma unroll
                        for (int j = 0; j < 6; ++j) c0[j] += seg[j + kc] * wcur[kc];
                }
                if (xr >= 1) {
#pragma unroll
                    for (int kc = 0; kc < 10; ++kc)
#pragma unroll
                        for (int j = 0; j < 6; ++j) c1[j] += seg[j + kc] * wprev[kc];
                }
                if (xr <= 9) {
#pragma unroll
                    for (int kc = 0; kc < 10; ++kc) wprev[kc] = wcur[kc];
                }
            }
            // SNU: s = relu(c + 0.8*s*(1-y)); y = sigmoid(s + bc)
#pragma unroll
            for (int j = 0; j < 6; ++j) {
                float sa = fmaxf(c0[j] + L_TAU_C * s1[0][j] * (1.f - y1[0][j]), 0.f);
                float sb = fmaxf(c1[j] + L_TAU_C * s1[1][j] * (1.f - y1[1][j]), 0.f);
                s1[0][j] = sa; s1[1][j] = sb;
                y1[0][j] = sigmoidf_(sa + bch);
                y1[1][j] = sigmoidf_(sb + bch);
            }
            // maxpool 2x2 + partial FC dot
#pragma unroll
            for (int pj = 0; pj < 3; ++pj) {
                float h = fmaxf(fmaxf(y1[0][2 * pj], y1[0][2 * pj + 1]),
                                fmaxf(y1[1][2 * pj], y1[1][2 * pj + 1]));
                p0 += h * w2r[pj][0];
                p1 += h * w2r[pj][1];
            }
        }
        // block reduce p0,p1 (inactive lanes contribute 0)
#pragma unroll
        for (int off = 32; off >= 1; off >>= 1) {
            p0 += __shfl_down(p0, off);
            p1 += __shfl_down(p1, off);
        }
        if (lane == 0) { red[wave * 2] = p0; red[wave * 2 + 1] = p1; }
        __syncthreads();
        if (tid == 0) {
            float q0 = red[0] + red[2] + red[4] + red[6];
            float q1 = red[1] + red[3] + red[5] + red[7];
            float* dst = part + ((size_t)t * 128 + b) * 12 + ch * 2;
            dst[0] = q0; dst[1] = q1;
        }
    }
}

// ---------------------------------------------------------------------------
// Kernel 3: s2/y2 recurrence, out_rec, m, loss, acc. One block, 128 threads.
// ---------------------------------------------------------------------------
__global__ __launch_bounds__(128) void k_final(const float* __restrict__ part,
                                               const void* __restrict__ yraw,
                                               const float* __restrict__ b2,
                                               float* __restrict__ out) {
    __shared__ float red[4];
    const int b = threadIdx.x;  // 0..127

    // labels may be int64 (reference) or int32: detect.
    const int* yi = (const int*)yraw;
    bool i64 = true;
    for (int k = 0; k < 64; ++k) {
        if (yi[2 * k + 1] != 0) { i64 = false; break; }
    }
    int lbl = i64 ? (int)((const long long*)yraw)[b] : yi[b];

    float b20 = b2[0], b21 = b2[1];
    float s20 = 0.f, s21 = 0.f, y20 = 0.f, y21 = 0.f, m0 = 0.f, m1 = 0.f;
    float* orec = out + 257 + b * 42;
    orec[0] = 0.f; orec[1] = 0.f;
    for (int t = 0; t < 20; ++t) {
        const float4* pp = reinterpret_cast<const float4*>(part + ((size_t)t * 128 + b) * 12);
        float4 a = pp[0], c = pp[1], d = pp[2];
        float sum0 = a.x + a.z + c.x + c.z + d.x + d.z;
        float sum1 = a.y + a.w + c.y + c.w + d.y + d.w;
        s20 = fmaxf(sum0 + L_TAU_C * s20 * (1.f - y20), 0.f);
        s21 = fmaxf(sum1 + L_TAU_C * s21 * (1.f - y21), 0.f);
        y20 = sigmoidf_(s20 + b20);
        y21 = sigmoidf_(s21 + b21);
        orec[(t + 1) * 2 + 0] = y20;
        orec[(t + 1) * 2 + 1] = y21;
        m0 += y20; m1 += y21;
    }
    m0 *= 0.05f; m1 *= 0.05f;
    out[1 + b * 2 + 0] = m0;
    out[1 + b * 2 + 1] = m1;

    float mx = fmaxf(m0, m1);
    float lse = mx + logf(expf(m0 - mx) + expf(m1 - mx));
    float lossc = -(((lbl != 0) ? m1 : m0) - lse);
    int pred = (m1 > m0) ? 1 : 0;
    float accc = (pred == lbl) ? 1.f : 0.f;
#pragma unroll
    for (int off = 32; off >= 1; off >>= 1) {
        lossc += __shfl_down(lossc, off);
        accc += __shfl_down(accc, off);
    }
    if ((b & 63) == 0) { red[(b >> 6) * 2] = lossc; red[(b >> 6) * 2 + 1] = accc; }
    __syncthreads();
    if (b == 0) {
        out[0] = (red[0] + red[2]) * (1.f / 128.f);
        out[5633] = (red[1] + red[3]) * (1.f / 128.f);
    }
}

extern "C" void kernel_launch(void* const* d_in, const int* in_sizes, int n_in,
                              void* d_out, int out_size, void* d_ws, size_t ws_size,
                              hipStream_t stream) {
    const float* x  = (const float*)d_in[0];
    const void*  y  = d_in[1];
    const float* Wc = (const float*)d_in[2];
    const float* bc = (const float*)d_in[3];
    const float* W2 = (const float*)d_in[4];
    const float* b2 = (const float*)d_in[5];
    float* out = (float*)d_out;

    const size_t xt_bytes = (size_t)128 * 20 * 4096 * 2;    // 20,971,520
    const size_t part_bytes = (size_t)20 * 128 * 6 * 2 * 4; // 245,760
    const int use16 = (ws_size >= xt_bytes + part_bytes) ? 1 : 0;

    _Float16* xT = (_Float16*)d_ws;
    float* part = use16 ? (float*)((char*)d_ws + xt_bytes) : (float*)d_ws;

    if (use16) {
        k_transpose16<<<2048, 256, 0, stream>>>(x, xT);
        k_conv_snu<1><<<768, 256, 0, stream>>>(x, xT, Wc, bc, W2, part);
    } else {
        k_conv_snu<0><<<768, 256, 0, stream>>>(x, (const _Float16*)d_ws, Wc, bc, W2, part);
    }
    k_final<<<1, 128, 0, stream>>>(part, y, b2, out);
}

// Round 5
// 161.491 us; speedup vs baseline: 4.3952x; 1.1328x over previous
//
#include <hip/hip_runtime.h>
#include <hip/hip_bf16.h>
#include <math.h>

#define L_TAU_C 0.8f

typedef _Float16 half2_t __attribute__((ext_vector_type(2)));

union U32H2 { unsigned int u; half2_t h; };
__device__ __forceinline__ half2_t h2(unsigned int v) { U32H2 x; x.u = v; return x.h; }

__device__ __forceinline__ float sigmoidf_(float x) {
    return 1.0f / (1.0f + __expf(-x));
}

// ---------------------------------------------------------------------------
// Kernel 1: transpose x [128][4096][20] f32 -> xT [128][20][4096] f16.
// ---------------------------------------------------------------------------
__global__ __launch_bounds__(256) void k_transpose16(const float* __restrict__ x,
                                                     _Float16* __restrict__ xT) {
    int gp = blockIdx.x * 256 + threadIdx.x;      // 0..524287
    int b = gp >> 12, p = gp & 4095;
    const float4* src = reinterpret_cast<const float4*>(x + (size_t)gp * 20);
    float v[20];
#pragma unroll
    for (int k = 0; k < 5; ++k) {
        float4 q = src[k];
        v[4 * k + 0] = q.x; v[4 * k + 1] = q.y; v[4 * k + 2] = q.z; v[4 * k + 3] = q.w;
    }
    _Float16* dst = xT + (size_t)b * 20 * 4096 + p;
#pragma unroll
    for (int t = 0; t < 20; ++t) dst[(size_t)t * 4096] = (_Float16)v[t];
}

// ---------------------------------------------------------------------------
// Staging helpers. LDS layout per buffer: copy A (halfs as-is) and copy B
// (halfs shifted left 2), each [64 rows][64 halfs], b64-unit XOR-swizzled:
// physical_unit = unit ^ sw2, sw2 = ((R>>1)&7)<<1 (even -> 16B stores stay
// contiguous; R>>1 because output rows step by 2 so R-parity is wave-uniform).
// ---------------------------------------------------------------------------
__device__ __forceinline__ void stageA_B(_Float16* bufA, _Float16* bufB,
                                         int e, uint4 pf) {
    int R = e >> 3, h = e & 7;
    int sw2 = ((R >> 1) & 7) << 1;
    int u2h = (2 * h) ^ sw2;                         // even
    // copy A: halfs 8h..8h+7 -> units 2h,2h+1 (adjacent after swizzle)
    *reinterpret_cast<uint4*>(&bufA[R * 64 + u2h * 4]) = pf;
    // copy B: value at col c stored at position c-2
    uint2 midv; midv.x = pf.y; midv.y = pf.z;        // cols 8h+2..8h+5 -> pos 8h..
    *reinterpret_cast<uint2*>(&bufB[R * 64 + u2h * 4]) = midv;
    *reinterpret_cast<unsigned int*>(&bufB[R * 64 + (u2h + 1) * 4]) = pf.w;
    if (h > 0) {
        int um = (2 * h - 1) ^ sw2;                  // odd unit
        *reinterpret_cast<unsigned int*>(&bufB[R * 64 + um * 4 + 2]) = pf.x;
    }
}

__device__ __forceinline__ void stage_scalar(_Float16* bufA, _Float16* bufB,
                                             const float* xb, int t, int tid) {
#pragma unroll
    for (int k = 0; k < 16; ++k) {
        int p = tid + k * 256;
        int R = p >> 6, c = p & 63;
        int sw2 = ((R >> 1) & 7) << 1;
        _Float16 v = (_Float16)xb[(size_t)p * 20 + t];
        bufA[R * 64 + (((c >> 2) ^ sw2) << 2) + (c & 3)] = v;
        if (c >= 2) {
            int q = c - 2;
            bufB[R * 64 + (((q >> 2) ^ sw2) << 2) + (q & 3)] = v;
        }
    }
}

// ---------------------------------------------------------------------------
// Kernel 2: fused conv + SNU(s1,y1) + maxpool + partial FC dot.
// Grid = 768 (b,ch) XCD-swizzled; block = 256 (4 waves), 243 active:
// thread = (pool row r 0..26, col group cg 0..8) -> 2 conv rows x 6 cols.
// f16 x in double-buffered dual-copy LDS; conv via v_dot2_f32_f16 with all
// 50 packed f16 weight pairs held in VGPRs (3 waves/SIMD -> VGPRs are free).
// One barrier per t; per-wave partials written straight to global.
// ---------------------------------------------------------------------------
template<int XMODE>   // 1 = f16 transposed input, 0 = strided fallback
__global__ __launch_bounds__(256, 3) void k_conv_snu(
    const float* __restrict__ x,      // [128][4096][20]
    const _Float16* __restrict__ xT,  // [128][20][4096]
    const float* __restrict__ Wc,     // [6][1][10][10]
    const float* __restrict__ bc,     // [6]
    const float* __restrict__ W2,     // [4374][2]
    float* __restrict__ partw)        // [20][128][6][4][2]
{
    __shared__ _Float16 xsh[2][2][64 * 64];   // 32 KB: [buf][copyA/B]
    __shared__ unsigned int wshw[52];

    const int tid = threadIdx.x;
    const int bi = blockIdx.x;
    const int xcd = bi & 7, slot = bi >> 3;
    const int b = (slot / 6) * 8 + xcd;   // all 6 ch of b on same XCD
    const int ch = slot % 6;

    // pack f16 weight pairs into LDS (then broadcast-load to VGPRs)
    if (tid < 50) {
        U32H2 p;
        p.h = half2_t{(_Float16)Wc[ch * 100 + 2 * tid],
                      (_Float16)Wc[ch * 100 + 2 * tid + 1]};
        wshw[tid] = p.u;
    }

    const bool active = tid < 243;
    const int r = tid / 9;            // pool row 0..26
    const int cg = tid % 9;           // col group 0..8, 6 conv cols each
    const int row0 = 2 * r;
    const int codd = cg & 1;          // odd cg reads copy B (start 6cg-2, 4-aligned)
    const int u0 = (6 * cg - 2 * codd) >> 2;

    float s1[2][6], y1[2][6];
#pragma unroll
    for (int i = 0; i < 2; ++i)
#pragma unroll
        for (int j = 0; j < 6; ++j) { s1[i][j] = 0.f; y1[i][j] = 0.f; }

    const float bch = bc[ch];

    float w2r[3][2];
#pragma unroll
    for (int pj = 0; pj < 3; ++pj) { w2r[pj][0] = 0.f; w2r[pj][1] = 0.f; }
    if (active) {
        int f0 = ch * 729 + r * 27 + cg * 3;
#pragma unroll
        for (int pj = 0; pj < 3; ++pj) {
            w2r[pj][0] = W2[(size_t)(f0 + pj) * 2 + 0];
            w2r[pj][1] = W2[(size_t)(f0 + pj) * 2 + 1];
        }
    }

    // ---- prologue: stage t=0 into buf0 ----
    const uint4* gsrc = reinterpret_cast<const uint4*>(xT + (size_t)b * 20 * 4096);
    if (XMODE == 1) {
#pragma unroll
        for (int k = 0; k < 2; ++k) {
            int e = tid + k * 256;
            uint4 pf = gsrc[e];
            stageA_B(&xsh[0][0][0], &xsh[0][1][0], e, pf);
        }
    } else {
        stage_scalar(&xsh[0][0][0], &xsh[0][1][0], x + (size_t)b * 4096 * 20, 0, tid);
    }
    __syncthreads();

    unsigned int wreg[50];
#pragma unroll
    for (int i = 0; i < 50; ++i) wreg[i] = wshw[i];

    for (int t = 0; t < 20; ++t) {
        // issue next-tile global loads EARLY (hide under compute)
        uint4 pf0, pf1;
        if (XMODE == 1 && t < 19) {
            pf0 = gsrc[(t + 1) * 512 + tid];
            pf1 = gsrc[(t + 1) * 512 + tid + 256];
        }

        float p0 = 0.f, p1 = 0.f;
        if (active) {
            const _Float16* cur = &xsh[t & 1][codd][0];
            float c0[6], c1[6];
#pragma unroll
            for (int j = 0; j < 6; ++j) { c0[j] = 0.f; c1[j] = 0.f; }

#pragma unroll
            for (int xr = 0; xr < 11; ++xr) {
                const int R = row0 + xr;
                const int sw2 = ((R >> 1) & 7) << 1;
                const _Float16* rowp = cur + R * 64;
                unsigned int s[8];
#pragma unroll
                for (int q = 0; q < 4; ++q) {
                    uint2 v = *reinterpret_cast<const uint2*>(
                        rowp + (((u0 + q) ^ sw2) << 2));
                    s[2 * q] = v.x; s[2 * q + 1] = v.y;
                }
                unsigned int ss[7];
#pragma unroll
                for (int i = 0; i < 7; ++i)
                    ss[i] = (s[i] >> 16) | (s[i + 1] << 16);   // v_alignbit

                if (xr <= 9) {
#pragma unroll
                    for (int m = 0; m < 5; ++m) {
                        half2_t w = h2(wreg[xr * 5 + m]);
                        c0[0] = __builtin_amdgcn_fdot2(h2(s[m]),      w, c0[0], false);
                        c0[2] = __builtin_amdgcn_fdot2(h2(s[m + 1]),  w, c0[2], false);
                        c0[4] = __builtin_amdgcn_fdot2(h2(s[m + 2]),  w, c0[4], false);
                        c0[1] = __builtin_amdgcn_fdot2(h2(ss[m]),     w, c0[1], false);
                        c0[3] = __builtin_amdgcn_fdot2(h2(ss[m + 1]), w, c0[3], false);
                        c0[5] = __builtin_amdgcn_fdot2(h2(ss[m + 2]), w, c0[5], false);
                    }
                }
                if (xr >= 1) {
#pragma unroll
                    for (int m = 0; m < 5; ++m) {
                        half2_t w = h2(wreg[(xr - 1) * 5 + m]);
                        c1[0] = __builtin_amdgcn_fdot2(h2(s[m]),      w, c1[0], false);
                        c1[2] = __builtin_amdgcn_fdot2(h2(s[m + 1]),  w, c1[2], false);
                        c1[4] = __builtin_amdgcn_fdot2(h2(s[m + 2]),  w, c1[4], false);
                        c1[1] = __builtin_amdgcn_fdot2(h2(ss[m]),     w, c1[1], false);
                        c1[3] = __builtin_amdgcn_fdot2(h2(ss[m + 1]), w, c1[3], false);
                        c1[5] = __builtin_amdgcn_fdot2(h2(ss[m + 2]), w, c1[5], false);
                    }
                }
            }
            // SNU: s = relu(c + 0.8*s*(1-y)); y = sigmoid(s + bc)
#pragma unroll
            for (int j = 0; j < 6; ++j) {
                float sa = fmaxf(c0[j] + L_TAU_C * s1[0][j] * (1.f - y1[0][j]), 0.f);
                float sb = fmaxf(c1[j] + L_TAU_C * s1[1][j] * (1.f - y1[1][j]), 0.f);
                s1[0][j] = sa; s1[1][j] = sb;
                y1[0][j] = sigmoidf_(sa + bch);
                y1[1][j] = sigmoidf_(sb + bch);
            }
            // maxpool 2x2 + partial FC dot
#pragma unroll
            for (int pj = 0; pj < 3; ++pj) {
                float h = fmaxf(fmaxf(y1[0][2 * pj], y1[0][2 * pj + 1]),
                                fmaxf(y1[1][2 * pj], y1[1][2 * pj + 1]));
                p0 += h * w2r[pj][0];
                p1 += h * w2r[pj][1];
            }
        }
        // wave reduce + direct global store of per-wave partials
#pragma unroll
        for (int off = 32; off >= 1; off >>= 1) {
            p0 += __shfl_down(p0, off);
            p1 += __shfl_down(p1, off);
        }
        if ((tid & 63) == 0) {
            float2 val; val.x = p0; val.y = p1;
            *reinterpret_cast<float2*>(
                &partw[((((size_t)t * 128 + b) * 6 + ch) * 4 + (tid >> 6)) * 2]) = val;
        }
        // write next tile into the other buffer
        if (t < 19) {
            _Float16* nA = &xsh[(t + 1) & 1][0][0];
            _Float16* nB = &xsh[(t + 1) & 1][1][0];
            if (XMODE == 1) {
                stageA_B(nA, nB, tid, pf0);
                stageA_B(nA, nB, tid + 256, pf1);
            } else {
                stage_scalar(nA, nB, x + (size_t)b * 4096 * 20, t + 1, tid);
            }
        }
        __syncthreads();
    }
}

// ---------------------------------------------------------------------------
// Kernel 3: s2/y2 recurrence, out_rec, m, loss, acc. One block, 128 threads.
// ---------------------------------------------------------------------------
__global__ __launch_bounds__(128) void k_final(const float* __restrict__ partw,
                                               const void* __restrict__ yraw,
                                               const float* __restrict__ b2,
                                               float* __restrict__ out) {
    __shared__ float red[4];
    const int b = threadIdx.x;  // 0..127

    // labels may be int64 (reference) or int32: detect.
    const int* yi = (const int*)yraw;
    bool i64 = true;
    for (int k = 0; k < 64; ++k) {
        if (yi[2 * k + 1] != 0) { i64 = false; break; }
    }
    int lbl = i64 ? (int)((const long long*)yraw)[b] : yi[b];

    float b20 = b2[0], b21 = b2[1];
    float s20 = 0.f, s21 = 0.f, y20 = 0.f, y21 = 0.f, m0 = 0.f, m1 = 0.f;
    float* orec = out + 257 + b * 42;
    orec[0] = 0.f; orec[1] = 0.f;
    for (int t = 0; t < 20; ++t) {
        const float4* pp = reinterpret_cast<const float4*>(
            partw + ((size_t)t * 128 + b) * 48);
        float sum0 = 0.f, sum1 = 0.f;
#pragma unroll
        for (int i = 0; i < 12; ++i) {
            float4 a = pp[i];
            sum0 += a.x + a.z;
            sum1 += a.y + a.w;
        }
        s20 = fmaxf(sum0 + L_TAU_C * s20 * (1.f - y20), 0.f);
        s21 = fmaxf(sum1 + L_TAU_C * s21 * (1.f - y21), 0.f);
        y20 = sigmoidf_(s20 + b20);
        y21 = sigmoidf_(s21 + b21);
        orec[(t + 1) * 2 + 0] = y20;
        orec[(t + 1) * 2 + 1] = y21;
        m0 += y20; m1 += y21;
    }
    m0 *= 0.05f; m1 *= 0.05f;
    out[1 + b * 2 + 0] = m0;
    out[1 + b * 2 + 1] = m1;

    float mx = fmaxf(m0, m1);
    float lse = mx + logf(expf(m0 - mx) + expf(m1 - mx));
    float lossc = -(((lbl != 0) ? m1 : m0) - lse);
    int pred = (m1 > m0) ? 1 : 0;
    float accc = (pred == lbl) ? 1.f : 0.f;
#pragma unroll
    for (int off = 32; off >= 1; off >>= 1) {
        lossc += __shfl_down(lossc, off);
        accc += __shfl_down(accc, off);
    }
    if ((b & 63) == 0) { red[(b >> 6) * 2] = lossc; red[(b >> 6) * 2 + 1] = accc; }
    __syncthreads();
    if (b == 0) {
        out[0] = (red[0] + red[2]) * (1.f / 128.f);
        out[5633] = (red[1] + red[3]) * (1.f / 128.f);
    }
}

extern "C" void kernel_launch(void* const* d_in, const int* in_sizes, int n_in,
                              void* d_out, int out_size, void* d_ws, size_t ws_size,
                              hipStream_t stream) {
    const float* x  = (const float*)d_in[0];
    const void*  y  = d_in[1];
    const float* Wc = (const float*)d_in[2];
    const float* bc = (const float*)d_in[3];
    const float* W2 = (const float*)d_in[4];
    const float* b2 = (const float*)d_in[5];
    float* out = (float*)d_out;

    const size_t xt_bytes = (size_t)128 * 20 * 4096 * 2;        // 20,971,520
    const size_t partw_bytes = (size_t)20 * 128 * 6 * 4 * 2 * 4; // 491,520
    const int use16 = (ws_size >= xt_bytes + partw_bytes) ? 1 : 0;

    _Float16* xT = (_Float16*)d_ws;
    float* partw = use16 ? (float*)((char*)d_ws + xt_bytes) : (float*)d_ws;

    if (use16) {
        k_transpose16<<<2048, 256, 0, stream>>>(x, xT);
        k_conv_snu<1><<<768, 256, 0, stream>>>(x, xT, Wc, bc, W2, partw);
    } else {
        k_conv_snu<0><<<768, 256, 0, stream>>>(x, (const _Float16*)d_ws, Wc, bc, W2, partw);
    }
    k_final<<<1, 128, 0, stream>>>(partw, y, b2, out);
}

// Round 6
// 155.713 us; speedup vs baseline: 4.5583x; 1.0371x over previous
//
#include <hip/hip_runtime.h>
#include <hip/hip_bf16.h>
#include <math.h>

#define L_TAU_C 0.8f

typedef _Float16 half2_t __attribute__((ext_vector_type(2)));

union U32H2 { unsigned int u; half2_t h; };
__device__ __forceinline__ half2_t h2(unsigned int v) { U32H2 x; x.u = v; return x.h; }

__device__ __forceinline__ float sigmoidf_(float x) {
    return 1.0f / (1.0f + __expf(-x));
}

// ---------------------------------------------------------------------------
// Kernel 1: transpose x [128][4096][20] f32 -> xT [128][20][4096] f16.
// ---------------------------------------------------------------------------
__global__ __launch_bounds__(256) void k_transpose16(const float* __restrict__ x,
                                                     _Float16* __restrict__ xT) {
    int gp = blockIdx.x * 256 + threadIdx.x;      // 0..524287
    int b = gp >> 12, p = gp & 4095;
    const float4* src = reinterpret_cast<const float4*>(x + (size_t)gp * 20);
    float v[20];
#pragma unroll
    for (int k = 0; k < 5; ++k) {
        float4 q = src[k];
        v[4 * k + 0] = q.x; v[4 * k + 1] = q.y; v[4 * k + 2] = q.z; v[4 * k + 3] = q.w;
    }
    _Float16* dst = xT + (size_t)b * 20 * 4096 + p;
#pragma unroll
    for (int t = 0; t < 20; ++t) dst[(size_t)t * 4096] = (_Float16)v[t];
}

// ---------------------------------------------------------------------------
// Staging helpers. LDS layout per buffer: copy A (halfs as-is) and copy B
// (halfs shifted left 2), each [64 rows][64 halfs], b64-unit XOR-swizzled:
// physical_unit = unit ^ sw2, sw2 = ((R>>1)&7)<<1 (even -> 16B stores stay
// contiguous; R>>1 because output rows step by 2 so R-parity is wave-uniform).
// ---------------------------------------------------------------------------
__device__ __forceinline__ void stageA_B(_Float16* bufA, _Float16* bufB,
                                         int e, uint4 pf) {
    int R = e >> 3, h = e & 7;
    int sw2 = ((R >> 1) & 7) << 1;
    int u2h = (2 * h) ^ sw2;                         // even
    // copy A: halfs 8h..8h+7 -> units 2h,2h+1 (adjacent after swizzle)
    *reinterpret_cast<uint4*>(&bufA[R * 64 + u2h * 4]) = pf;
    // copy B: value at col c stored at position c-2
    uint2 midv; midv.x = pf.y; midv.y = pf.z;        // cols 8h+2..8h+5 -> pos 8h..
    *reinterpret_cast<uint2*>(&bufB[R * 64 + u2h * 4]) = midv;
    *reinterpret_cast<unsigned int*>(&bufB[R * 64 + (u2h + 1) * 4]) = pf.w;
    if (h > 0) {
        int um = (2 * h - 1) ^ sw2;                  // odd unit
        *reinterpret_cast<unsigned int*>(&bufB[R * 64 + um * 4 + 2]) = pf.x;
    }
}

__device__ __forceinline__ void stage_scalar(_Float16* bufA, _Float16* bufB,
                                             const float* xb, int t, int tid) {
#pragma unroll
    for (int k = 0; k < 16; ++k) {
        int p = tid + k * 256;
        int R = p >> 6, c = p & 63;
        int sw2 = ((R >> 1) & 7) << 1;
        _Float16 v = (_Float16)xb[(size_t)p * 20 + t];
        bufA[R * 64 + (((c >> 2) ^ sw2) << 2) + (c & 3)] = v;
        if (c >= 2) {
            int q = c - 2;
            bufB[R * 64 + (((q >> 2) ^ sw2) << 2) + (q & 3)] = v;
        }
    }
}

// ---------------------------------------------------------------------------
// Kernel 2: fused conv + SNU(s1,y1) + maxpool + partial FC dot.
// Grid = 768 (b,ch) XCD-swizzled; block = 256 (4 waves), 243 active:
// thread = (pool row r 0..26, col group cg 0..8) -> 2 conv rows x 6 cols.
// f16 x in double-buffered dual-copy LDS; conv via v_dot2_f32_f16.
// Weights: packed half2 pairs in LDS, broadcast-loaded PER ROW inside the
// unrolled loop (5 u32/row); previous row carried in 5 regs (SSA renames).
// NO register weight array (R5's wreg[50] spilled to scratch: WRITE_SIZE
// 160KB->9.7MB at VGPR=84 -- the array went to scratch, each use a
// buffer_load+vmcnt chained into the dot stream).
// One barrier per t; per-wave partials written straight to global.
// ---------------------------------------------------------------------------
template<int XMODE>   // 1 = f16 transposed input, 0 = strided fallback
__global__ __launch_bounds__(256, 3) void k_conv_snu(
    const float* __restrict__ x,      // [128][4096][20]
    const _Float16* __restrict__ xT,  // [128][20][4096]
    const float* __restrict__ Wc,     // [6][1][10][10]
    const float* __restrict__ bc,     // [6]
    const float* __restrict__ W2,     // [4374][2]
    float* __restrict__ partw)        // [20][128][6][4][2]
{
    __shared__ _Float16 xsh[2][2][64 * 64];   // 32 KB: [buf][copyA/B]
    __shared__ unsigned int wshw[52];

    const int tid = threadIdx.x;
    const int bi = blockIdx.x;
    const int xcd = bi & 7, slot = bi >> 3;
    const int b = (slot / 6) * 8 + xcd;   // all 6 ch of b on same XCD
    const int ch = slot % 6;

    // pack f16 weight pairs into LDS
    if (tid < 50) {
        U32H2 p;
        p.h = half2_t{(_Float16)Wc[ch * 100 + 2 * tid],
                      (_Float16)Wc[ch * 100 + 2 * tid + 1]};
        wshw[tid] = p.u;
    }

    const bool active = tid < 243;
    const int r = tid / 9;            // pool row 0..26
    const int cg = tid % 9;           // col group 0..8, 6 conv cols each
    const int row0 = 2 * r;
    const int codd = cg & 1;          // odd cg reads copy B (start 6cg-2, 4-aligned)
    const int u0 = (6 * cg - 2 * codd) >> 2;

    float s1[2][6], y1[2][6];
#pragma unroll
    for (int i = 0; i < 2; ++i)
#pragma unroll
        for (int j = 0; j < 6; ++j) { s1[i][j] = 0.f; y1[i][j] = 0.f; }

    const float bch = bc[ch];

    float w2r[3][2];
#pragma unroll
    for (int pj = 0; pj < 3; ++pj) { w2r[pj][0] = 0.f; w2r[pj][1] = 0.f; }
    if (active) {
        int f0 = ch * 729 + r * 27 + cg * 3;
#pragma unroll
        for (int pj = 0; pj < 3; ++pj) {
            w2r[pj][0] = W2[(size_t)(f0 + pj) * 2 + 0];
            w2r[pj][1] = W2[(size_t)(f0 + pj) * 2 + 1];
        }
    }

    // ---- prologue: stage t=0 into buf0 ----
    const uint4* gsrc = reinterpret_cast<const uint4*>(xT + (size_t)b * 20 * 4096);
    if (XMODE == 1) {
#pragma unroll
        for (int k = 0; k < 2; ++k) {
            int e = tid + k * 256;
            uint4 pf = gsrc[e];
            stageA_B(&xsh[0][0][0], &xsh[0][1][0], e, pf);
        }
    } else {
        stage_scalar(&xsh[0][0][0], &xsh[0][1][0], x + (size_t)b * 4096 * 20, 0, tid);
    }
    __syncthreads();

    for (int t = 0; t < 20; ++t) {
        // issue next-tile global loads EARLY (hide under compute)
        uint4 pf0, pf1;
        if (XMODE == 1 && t < 19) {
            pf0 = gsrc[(t + 1) * 512 + tid];
            pf1 = gsrc[(t + 1) * 512 + tid + 256];
        }

        float p0 = 0.f, p1 = 0.f;
        if (active) {
            const _Float16* cur = &xsh[t & 1][codd][0];
            float c0[6], c1[6];
#pragma unroll
            for (int j = 0; j < 6; ++j) { c0[j] = 0.f; c1[j] = 0.f; }
            unsigned int wprev[5];

#pragma unroll
            for (int xr = 0; xr < 11; ++xr) {
                const int R = row0 + xr;
                const int sw2 = ((R >> 1) & 7) << 1;
                const _Float16* rowp = cur + R * 64;
                unsigned int s[8];
#pragma unroll
                for (int q = 0; q < 4; ++q) {
                    uint2 v = *reinterpret_cast<const uint2*>(
                        rowp + (((u0 + q) ^ sw2) << 2));
                    s[2 * q] = v.x; s[2 * q + 1] = v.y;
                }
                unsigned int ss[7];
#pragma unroll
                for (int i = 0; i < 7; ++i)
                    ss[i] = (s[i] >> 16) | (s[i + 1] << 16);   // v_alignbit

                unsigned int wcur[5];
                if (xr <= 9) {
#pragma unroll
                    for (int m = 0; m < 5; ++m) wcur[m] = wshw[xr * 5 + m];
#pragma unroll
                    for (int m = 0; m < 5; ++m) {
                        half2_t w = h2(wcur[m]);
                        c0[0] = __builtin_amdgcn_fdot2(h2(s[m]),      w, c0[0], false);
                        c0[2] = __builtin_amdgcn_fdot2(h2(s[m + 1]),  w, c0[2], false);
                        c0[4] = __builtin_amdgcn_fdot2(h2(s[m + 2]),  w, c0[4], false);
                        c0[1] = __builtin_amdgcn_fdot2(h2(ss[m]),     w, c0[1], false);
                        c0[3] = __builtin_amdgcn_fdot2(h2(ss[m + 1]), w, c0[3], false);
                        c0[5] = __builtin_amdgcn_fdot2(h2(ss[m + 2]), w, c0[5], false);
                    }
                }
                if (xr >= 1) {
#pragma unroll
                    for (int m = 0; m < 5; ++m) {
                        half2_t w = h2(wprev[m]);
                        c1[0] = __builtin_amdgcn_fdot2(h2(s[m]),      w, c1[0], false);
                        c1[2] = __builtin_amdgcn_fdot2(h2(s[m + 1]),  w, c1[2], false);
                        c1[4] = __builtin_amdgcn_fdot2(h2(s[m + 2]),  w, c1[4], false);
                        c1[1] = __builtin_amdgcn_fdot2(h2(ss[m]),     w, c1[1], false);
                        c1[3] = __builtin_amdgcn_fdot2(h2(ss[m + 1]), w, c1[3], false);
                        c1[5] = __builtin_amdgcn_fdot2(h2(ss[m + 2]), w, c1[5], false);
                    }
                }
                if (xr <= 9) {
#pragma unroll
                    for (int m = 0; m < 5; ++m) wprev[m] = wcur[m];
                }
            }
            // SNU: s = relu(c + 0.8*s*(1-y)); y = sigmoid(s + bc)
#pragma unroll
            for (int j = 0; j < 6; ++j) {
                float sa = fmaxf(c0[j] + L_TAU_C * s1[0][j] * (1.f - y1[0][j]), 0.f);
                float sb = fmaxf(c1[j] + L_TAU_C * s1[1][j] * (1.f - y1[1][j]), 0.f);
                s1[0][j] = sa; s1[1][j] = sb;
                y1[0][j] = sigmoidf_(sa + bch);
                y1[1][j] = sigmoidf_(sb + bch);
            }
            // maxpool 2x2 + partial FC dot
#pragma unroll
            for (int pj = 0; pj < 3; ++pj) {
                float h = fmaxf(fmaxf(y1[0][2 * pj], y1[0][2 * pj + 1]),
                                fmaxf(y1[1][2 * pj], y1[1][2 * pj + 1]));
                p0 += h * w2r[pj][0];
                p1 += h * w2r[pj][1];
            }
        }
        // wave reduce + direct global store of per-wave partials
#pragma unroll
        for (int off = 32; off >= 1; off >>= 1) {
            p0 += __shfl_down(p0, off);
            p1 += __shfl_down(p1, off);
        }
        if ((tid & 63) == 0) {
            float2 val; val.x = p0; val.y = p1;
            *reinterpret_cast<float2*>(
                &partw[((((size_t)t * 128 + b) * 6 + ch) * 4 + (tid >> 6)) * 2]) = val;
        }
        // write next tile into the other buffer
        if (t < 19) {
            _Float16* nA = &xsh[(t + 1) & 1][0][0];
            _Float16* nB = &xsh[(t + 1) & 1][1][0];
            if (XMODE == 1) {
                stageA_B(nA, nB, tid, pf0);
                stageA_B(nA, nB, tid + 256, pf1);
            } else {
                stage_scalar(nA, nB, x + (size_t)b * 4096 * 20, t + 1, tid);
            }
        }
        __syncthreads();
    }
}

// ---------------------------------------------------------------------------
// Kernel 3: s2/y2 recurrence, out_rec, m, loss, acc. One block, 128 threads.
// ---------------------------------------------------------------------------
__global__ __launch_bounds__(128) void k_final(const float* __restrict__ partw,
                                               const void* __restrict__ yraw,
                                               const float* __restrict__ b2,
                                               float* __restrict__ out) {
    __shared__ float red[4];
    const int b = threadIdx.x;  // 0..127

    // labels may be int64 (reference) or int32: detect.
    const int* yi = (const int*)yraw;
    bool i64 = true;
    for (int k = 0; k < 64; ++k) {
        if (yi[2 * k + 1] != 0) { i64 = false; break; }
    }
    int lbl = i64 ? (int)((const long long*)yraw)[b] : yi[b];

    float b20 = b2[0], b21 = b2[1];
    float s20 = 0.f, s21 = 0.f, y20 = 0.f, y21 = 0.f, m0 = 0.f, m1 = 0.f;
    float* orec = out + 257 + b * 42;
    orec[0] = 0.f; orec[1] = 0.f;
    for (int t = 0; t < 20; ++t) {
        const float4* pp = reinterpret_cast<const float4*>(
            partw + ((size_t)t * 128 + b) * 48);
        float sum0 = 0.f, sum1 = 0.f;
#pragma unroll
        for (int i = 0; i < 12; ++i) {
            float4 a = pp[i];
            sum0 += a.x + a.z;
            sum1 += a.y + a.w;
        }
        s20 = fmaxf(sum0 + L_TAU_C * s20 * (1.f - y20), 0.f);
        s21 = fmaxf(sum1 + L_TAU_C * s21 * (1.f - y21), 0.f);
        y20 = sigmoidf_(s20 + b20);
        y21 = sigmoidf_(s21 + b21);
        orec[(t + 1) * 2 + 0] = y20;
        orec[(t + 1) * 2 + 1] = y21;
        m0 += y20; m1 += y21;
    }
    m0 *= 0.05f; m1 *= 0.05f;
    out[1 + b * 2 + 0] = m0;
    out[1 + b * 2 + 1] = m1;

    float mx = fmaxf(m0, m1);
    float lse = mx + logf(expf(m0 - mx) + expf(m1 - mx));
    float lossc = -(((lbl != 0) ? m1 : m0) - lse);
    int pred = (m1 > m0) ? 1 : 0;
    float accc = (pred == lbl) ? 1.f : 0.f;
#pragma unroll
    for (int off = 32; off >= 1; off >>= 1) {
        lossc += __shfl_down(lossc, off);
        accc += __shfl_down(accc, off);
    }
    if ((b & 63) == 0) { red[(b >> 6) * 2] = lossc; red[(b >> 6) * 2 + 1] = accc; }
    __syncthreads();
    if (b == 0) {
        out[0] = (red[0] + red[2]) * (1.f / 128.f);
        out[5633] = (red[1] + red[3]) * (1.f / 128.f);
    }
}

extern "C" void kernel_launch(void* const* d_in, const int* in_sizes, int n_in,
                              void* d_out, int out_size, void* d_ws, size_t ws_size,
                              hipStream_t stream) {
    const float* x  = (const float*)d_in[0];
    const void*  y  = d_in[1];
    const float* Wc = (const float*)d_in[2];
    const float* bc = (const float*)d_in[3];
    const float* W2 = (const float*)d_in[4];
    const float* b2 = (const float*)d_in[5];
    float* out = (float*)d_out;

    const size_t xt_bytes = (size_t)128 * 20 * 4096 * 2;        // 20,971,520
    const size_t partw_bytes = (size_t)20 * 128 * 6 * 4 * 2 * 4; // 491,520
    const int use16 = (ws_size >= xt_bytes + partw_bytes) ? 1 : 0;

    _Float16* xT = (_Float16*)d_ws;
    float* partw = use16 ? (float*)((char*)d_ws + xt_bytes) : (float*)d_ws;

    if (use16) {
        k_transpose16<<<2048, 256, 0, stream>>>(x, xT);
        k_conv_snu<1><<<768, 256, 0, stream>>>(x, xT, Wc, bc, W2, partw);
    } else {
        k_conv_snu<0><<<768, 256, 0, stream>>>(x, (const _Float16*)d_ws, Wc, bc, W2, partw);
    }
    k_final<<<1, 128, 0, stream>>>(partw, y, b2, out);
}